// Round 11
// baseline (119.399 us; speedup 1.0000x reference)
//
#include <hip/hip_runtime.h>

#define EPS_F 1e-6f

typedef float f32x4 __attribute__((ext_vector_type(4)));

__device__ __forceinline__ void mueller_vals(float ci, float eta,
                                             float& a, float& b,
                                             float& cc, float& cs)
{
    float rcp_eta = 1.0f / eta;
    bool  outside = (ci >= 0.0f);
    float eta_it = outside ? eta : rcp_eta;
    float eta_ti = outside ? rcp_eta : eta;

    float cts    = 1.0f - eta_ti * eta_ti * (1.0f - ci * ci);
    float ci_abs = fabsf(ci);

    // sqrtz: complex sqrt of (cts + EPS + 0j), then mulsign by sign(cts)
    float x   = cts + EPS_F;
    float sgn = (cts >= 0.0f) ? 1.0f : -1.0f;
    float ctt_re, ctt_im;
    if (x >= 0.0f) { ctt_re = sqrtf(x) * sgn;  ctt_im = 0.0f; }
    else           { ctt_re = 0.0f;            ctt_im = sqrtf(-x) * sgn; }

    float A    = ci_abs;
    float u_re = eta_it * ctt_re;
    float u_im = eta_it * ctt_im;
    float ds2  = (A + u_re) * (A + u_re) + u_im * u_im;
    float inv_ds = 1.0f / ds2;
    float as_re = (A * A - u_re * u_re - u_im * u_im) * inv_ds;
    float as_im = (-2.0f * A * u_im) * inv_ds;

    float B    = eta_it * ci_abs;
    float dp2  = (B + ctt_re) * (B + ctt_re) + ctt_im * ctt_im;
    float inv_dp = 1.0f / dp2;
    float ap_re = (B * B - ctt_re * ctt_re - ctt_im * ctt_im) * inv_dp;
    float ap_im = (-2.0f * B * ctt_im) * inv_dp;

    if (eta == 1.0f || eta == 0.0f) {     // dead for these inputs; fidelity
        as_re = as_im = ap_re = ap_im = 0.0f;
    }

    float r_s  = as_re * as_re + as_im * as_im;
    float r_p  = ap_re * ap_re + ap_im * ap_im;
    float prod = r_p * r_s;

    float s    = sqrtf(prod + EPS_F);     // c >= 1e-3 here; c==0 guard dead
    float norm = (prod == 0.0f) ? 0.0f : 1.0f / s;
    float cos_d = (ap_re * as_re + ap_im * as_im) * norm;
    float sin_d = (ap_im * as_re - ap_re * as_im) * norm;

    a  = 0.5f * (r_s + r_p);
    b  = 0.5f * (r_s - r_p);
    cc = s * cos_d;
    cs = s * cs == 0 ? s * sin_d : s * sin_d; // (kept simple below)
}

// Phase 1: 256 rays/block -> one ds_write_b128 per thread: {a,b,cc,cs}.
// Phase 2: dword sweep, 4-dense-line wave stores (round-8 shape).
// NEW (round 11): bijective XCD-contiguous block swizzle -- blocks on the
// same XCD process consecutive 16KB chunks, so each XCD's L2 emits one
// contiguous multi-MB write stream to HBM (fill-like), instead of 8-way
// interleaved 16KB stripes.
__global__ __launch_bounds__(256) void mueller_kernel(
    const float* __restrict__ ci_p,
    const float* __restrict__ eta_p,
    float* __restrict__ out, int n, int cpx /* chunks per XCD */)
{
    __shared__ float lds[256 * 4];

    int bid  = blockIdx.x;
    int nb   = gridDim.x;
    int sw;
    if ((nb & 7) == 0) {
        sw = (bid & 7) * (nb >> 3) + (bid >> 3);   // bijective XCD swizzle
    } else {
        sw = bid;                                   // safety (not hit: 32768%8==0)
    }

    int t    = threadIdx.x;
    int ray0 = sw << 8;
    int ray  = ray0 + t;

    if (ray < n) {
        float ci  = ci_p[ray];
        float eta = eta_p[ray];
        float a, b, cc, cs;
        {
            float rcp_eta = 1.0f / eta;
            bool  outside = (ci >= 0.0f);
            float eta_it = outside ? eta : rcp_eta;
            float eta_ti = outside ? rcp_eta : eta;

            float cts    = 1.0f - eta_ti * eta_ti * (1.0f - ci * ci);
            float ci_abs = fabsf(ci);

            float x   = cts + EPS_F;
            float sgn = (cts >= 0.0f) ? 1.0f : -1.0f;
            float ctt_re, ctt_im;
            if (x >= 0.0f) { ctt_re = sqrtf(x) * sgn;  ctt_im = 0.0f; }
            else           { ctt_re = 0.0f;            ctt_im = sqrtf(-x) * sgn; }

            float A    = ci_abs;
            float u_re = eta_it * ctt_re;
            float u_im = eta_it * ctt_im;
            float ds2  = (A + u_re) * (A + u_re) + u_im * u_im;
            float inv_ds = 1.0f / ds2;
            float as_re = (A * A - u_re * u_re - u_im * u_im) * inv_ds;
            float as_im = (-2.0f * A * u_im) * inv_ds;

            float B    = eta_it * ci_abs;
            float dp2  = (B + ctt_re) * (B + ctt_re) + ctt_im * ctt_im;
            float inv_dp = 1.0f / dp2;
            float ap_re = (B * B - ctt_re * ctt_re - ctt_im * ctt_im) * inv_dp;
            float ap_im = (-2.0f * B * ctt_im) * inv_dp;

            if (eta == 1.0f || eta == 0.0f) {
                as_re = as_im = ap_re = ap_im = 0.0f;
            }

            float r_s  = as_re * as_re + as_im * as_im;
            float r_p  = ap_re * ap_re + ap_im * ap_im;
            float prod = r_p * r_s;

            float s    = sqrtf(prod + EPS_F);
            float norm = (prod == 0.0f) ? 0.0f : 1.0f / s;
            float cos_d = (ap_re * as_re + ap_im * as_im) * norm;
            float sin_d = (ap_im * as_re - ap_re * as_im) * norm;

            a  = 0.5f * (r_s + r_p);
            b  = 0.5f * (r_s - r_p);
            cc = s * cos_d;
            cs = s * sin_d;
        }
        *reinterpret_cast<f32x4*>(&lds[t << 2]) = (f32x4){a, b, cc, cs};
    }
    __syncthreads();

    // elem e = t&15 of [a b 0 0; b a 0 0; 0 0 cc -cs; 0 0 cs cc]
    int   e    = t & 15;
    int   comp = ((e >> 3) << 1) + ((e & 1) ^ ((e >> 2) & 1));
    bool  nz   = (((e >> 1) & 1) == ((e >> 3) & 1));
    float m    = nz ? ((e == 11) ? -1.0f : 1.0f) : 0.0f;

    int    lbase = ((t >> 4) << 2) + comp;            // += 64 per k
    float* ob    = out + ((size_t)ray0 << 4) + t;     // += 256 per k

    if (ray0 + 256 <= n) {
        #pragma unroll
        for (int k = 0; k < 16; ++k)
            ob[k << 8] = m * lds[lbase + (k << 6)];
    } else {
        for (int k = 0; k < 16; ++k) {
            int rl = (t >> 4) + (k << 4);
            if (ray0 + rl < n)
                ob[k << 8] = m * lds[lbase + (k << 6)];
        }
    }
}

extern "C" void kernel_launch(void* const* d_in, const int* in_sizes, int n_in,
                              void* d_out, int out_size, void* d_ws, size_t ws_size,
                              hipStream_t stream) {
    const float* ci  = (const float*)d_in[0];
    const float* eta = (const float*)d_in[1];
    float* out = (float*)d_out;
    int n = in_sizes[0];
    int block = 256;
    int grid = (n + block - 1) / block;    // 32768 for n=8.39M (divisible by 8)
    mueller_kernel<<<grid, block, 0, stream>>>(ci, eta, out, n, grid / 8);
}

// Round 12
// 115.756 us; speedup vs baseline: 1.0315x; 1.0315x over previous
//
#include <hip/hip_runtime.h>

#define EPS_F 1e-6f

typedef float f32x4 __attribute__((ext_vector_type(4)));

__device__ __forceinline__ void mueller_vals(float ci, float eta,
                                             float& a, float& b,
                                             float& cc, float& cs)
{
    float rcp_eta = 1.0f / eta;
    bool  outside = (ci >= 0.0f);
    float eta_it = outside ? eta : rcp_eta;
    float eta_ti = outside ? rcp_eta : eta;

    float cts    = 1.0f - eta_ti * eta_ti * (1.0f - ci * ci);
    float ci_abs = fabsf(ci);

    // sqrtz: complex sqrt of (cts + EPS + 0j), then mulsign by sign(cts)
    float x   = cts + EPS_F;
    float sgn = (cts >= 0.0f) ? 1.0f : -1.0f;
    float ctt_re, ctt_im;
    if (x >= 0.0f) { ctt_re = sqrtf(x) * sgn;  ctt_im = 0.0f; }
    else           { ctt_re = 0.0f;            ctt_im = sqrtf(-x) * sgn; }

    float A    = ci_abs;
    float u_re = eta_it * ctt_re;
    float u_im = eta_it * ctt_im;
    float ds2  = (A + u_re) * (A + u_re) + u_im * u_im;
    float inv_ds = 1.0f / ds2;
    float as_re = (A * A - u_re * u_re - u_im * u_im) * inv_ds;
    float as_im = (-2.0f * A * u_im) * inv_ds;

    float B    = eta_it * ci_abs;
    float dp2  = (B + ctt_re) * (B + ctt_re) + ctt_im * ctt_im;
    float inv_dp = 1.0f / dp2;
    float ap_re = (B * B - ctt_re * ctt_re - ctt_im * ctt_im) * inv_dp;
    float ap_im = (-2.0f * B * ctt_im) * inv_dp;

    if (eta == 1.0f || eta == 0.0f) {     // dead for these inputs; fidelity
        as_re = as_im = ap_re = ap_im = 0.0f;
    }

    float r_s  = as_re * as_re + as_im * as_im;
    float r_p  = ap_re * ap_re + ap_im * ap_im;
    float prod = r_p * r_s;

    float s    = sqrtf(prod + EPS_F);     // c >= 1e-3 here; c==0 guard dead
    float norm = (prod == 0.0f) ? 0.0f : 1.0f / s;
    float cos_d = (ap_re * as_re + ap_im * as_im) * norm;
    float sin_d = (ap_im * as_re - ap_re * as_im) * norm;

    a  = 0.5f * (r_s + r_p);
    b  = 0.5f * (r_s - r_p);
    cc = s * cos_d;
    cs = s * sin_d;
}

// 1024 rays/block (4 per thread):
// Phase 1: two dwordx4 input loads + 4 independent compute chains ->
//          4x ds_write_b128 of {a,b,cc,cs}. One HBM-latency exposure
//          per 64 store-iterations (was per 16) -> store duty cycle x4.
// Phase 2: dword sweep of the block's 64KB region; each wave-instr writes
//          64 consecutive dwords = 4 dense lines (round-8 proven shape).
__global__ __launch_bounds__(256) void mueller_kernel(
    const float* __restrict__ ci_p,
    const float* __restrict__ eta_p,
    float* __restrict__ out, int n)
{
    __shared__ float lds[1024 * 4];        // 16 KB

    int t    = threadIdx.x;
    int ray0 = blockIdx.x << 10;
    int r4   = ray0 + (t << 2);

    if (r4 + 3 < n) {                      // fast path: vectorized loads
        f32x4 civ = *reinterpret_cast<const f32x4*>(ci_p + r4);
        f32x4 etv = *reinterpret_cast<const f32x4*>(eta_p + r4);
        #pragma unroll
        for (int j = 0; j < 4; ++j) {
            float a, b, cc, cs;
            mueller_vals(civ[j], etv[j], a, b, cc, cs);
            *reinterpret_cast<f32x4*>(&lds[(t << 4) + (j << 2)]) =
                (f32x4){a, b, cc, cs};
        }
    } else {                               // tail: per-ray guarded
        for (int j = 0; j < 4; ++j) {
            int r = r4 + j;
            if (r < n) {
                float a, b, cc, cs;
                mueller_vals(ci_p[r], eta_p[r], a, b, cc, cs);
                *reinterpret_cast<f32x4*>(&lds[(t << 4) + (j << 2)]) =
                    (f32x4){a, b, cc, cs};
            }
        }
    }
    __syncthreads();

    // elem e = t&15 of [a b 0 0; b a 0 0; 0 0 cc -cs; 0 0 cs cc]
    int   e    = t & 15;
    int   comp = ((e >> 3) << 1) + ((e & 1) ^ ((e >> 2) & 1));
    bool  nz   = (((e >> 1) & 1) == ((e >> 3) & 1));
    float m    = nz ? ((e == 11) ? -1.0f : 1.0f) : 0.0f;

    // wave reads 16 distinct dwords (banks 0-15), 4-lane same-addr broadcast
    int    lbase = ((t >> 4) << 2) + comp;            // += 64 dwords per k
    float* ob    = out + ((size_t)ray0 << 4) + t;     // += 256 dwords per k

    if (ray0 + 1024 <= n) {                           // full block
        #pragma unroll
        for (int k = 0; k < 64; ++k)
            ob[k << 8] = m * lds[lbase + (k << 6)];
    } else {                                          // tail block
        for (int k = 0; k < 64; ++k) {
            int rl = (t >> 4) + (k << 4);
            if (ray0 + rl < n)
                ob[k << 8] = m * lds[lbase + (k << 6)];
        }
    }
}

extern "C" void kernel_launch(void* const* d_in, const int* in_sizes, int n_in,
                              void* d_out, int out_size, void* d_ws, size_t ws_size,
                              hipStream_t stream) {
    const float* ci  = (const float*)d_in[0];
    const float* eta = (const float*)d_in[1];
    float* out = (float*)d_out;
    int n = in_sizes[0];
    int block = 256;
    int grid = (n + 1023) >> 10;           // 1024 rays per block
    mueller_kernel<<<grid, block, 0, stream>>>(ci, eta, out, n);
}

// Round 13
// 108.219 us; speedup vs baseline: 1.1033x; 1.0696x over previous
//
#include <hip/hip_runtime.h>

#define EPS_F 1e-6f

typedef float f32x4 __attribute__((ext_vector_type(4)));

__device__ __forceinline__ void mueller_vals(float ci, float eta,
                                             float& a, float& b,
                                             float& cc, float& cs)
{
    float rcp_eta = 1.0f / eta;
    bool  outside = (ci >= 0.0f);
    float eta_it = outside ? eta : rcp_eta;
    float eta_ti = outside ? rcp_eta : eta;

    float cts    = 1.0f - eta_ti * eta_ti * (1.0f - ci * ci);
    float ci_abs = fabsf(ci);

    // sqrtz: complex sqrt of (cts + EPS + 0j), then mulsign by sign(cts)
    float x   = cts + EPS_F;
    float sgn = (cts >= 0.0f) ? 1.0f : -1.0f;
    float ctt_re, ctt_im;
    if (x >= 0.0f) { ctt_re = sqrtf(x) * sgn;  ctt_im = 0.0f; }
    else           { ctt_re = 0.0f;            ctt_im = sqrtf(-x) * sgn; }

    float A    = ci_abs;
    float u_re = eta_it * ctt_re;
    float u_im = eta_it * ctt_im;
    float ds2  = (A + u_re) * (A + u_re) + u_im * u_im;
    float inv_ds = 1.0f / ds2;
    float as_re = (A * A - u_re * u_re - u_im * u_im) * inv_ds;
    float as_im = (-2.0f * A * u_im) * inv_ds;

    float B    = eta_it * ci_abs;
    float dp2  = (B + ctt_re) * (B + ctt_re) + ctt_im * ctt_im;
    float inv_dp = 1.0f / dp2;
    float ap_re = (B * B - ctt_re * ctt_re - ctt_im * ctt_im) * inv_dp;
    float ap_im = (-2.0f * B * ctt_im) * inv_dp;

    if (eta == 1.0f || eta == 0.0f) {     // dead for these inputs; fidelity
        as_re = as_im = ap_re = ap_im = 0.0f;
    }

    float r_s  = as_re * as_re + as_im * as_im;
    float r_p  = ap_re * ap_re + ap_im * ap_im;
    float prod = r_p * r_s;

    float s    = sqrtf(prod + EPS_F);     // c >= 1e-3 here; c==0 guard dead
    float norm = (prod == 0.0f) ? 0.0f : 1.0f / s;
    float cos_d = (ap_re * as_re + ap_im * as_im) * norm;
    float sin_d = (ap_im * as_re - ap_re * as_im) * norm;

    a  = 0.5f * (r_s + r_p);
    b  = 0.5f * (r_s - r_p);
    cc = s * cos_d;
    cs = s * sin_d;
}

// FINAL (round-10 optimum, 104.7us = 5.77 TB/s effective):
// Phase 1: 256 rays/block -> one ds_write_b128 per thread: {a,b,cc,cs}.
// Phase 2: dword sweep of the block's 16KB output region; each wave-instr
//          writes 64 consecutive dwords = 4 dense cache lines (the store
//          transaction shape that unlocked the fill-like write path, r8:
//          171->108us). ds_read_b32 per dword: 16 distinct dwords/wave ->
//          16 banks, conflict-free; 16-lane same-address broadcast free.
// Falsified levers: nt-stores (2x min-burst waste), per-thread store MLP,
// grid-stride persistence, XCD-contiguous writes (-14%: defeats channel
// interleave), 1024-ray blocks (-10%: loses block-level latency hiding).
__global__ __launch_bounds__(256) void mueller_kernel(
    const float* __restrict__ ci_p,
    const float* __restrict__ eta_p,
    float* __restrict__ out, int n)
{
    __shared__ float lds[256 * 4];

    int t    = threadIdx.x;
    int ray0 = blockIdx.x << 8;
    int ray  = ray0 + t;

    if (ray < n) {
        float a, b, cc, cs;
        mueller_vals(ci_p[ray], eta_p[ray], a, b, cc, cs);
        *reinterpret_cast<f32x4*>(&lds[t << 2]) = (f32x4){a, b, cc, cs};
    }
    __syncthreads();

    // Per-thread fixed role: elem e = t&15 of the 4x4 row-major matrix
    //   [a b 0 0; b a 0 0; 0 0 cc -cs; 0 0 cs cc]
    // value = m * lds[ray][comp]
    int   e    = t & 15;
    int   comp = ((e >> 3) << 1) + ((e & 1) ^ ((e >> 2) & 1));
    bool  nz   = (((e >> 1) & 1) == ((e >> 3) & 1));
    float m    = nz ? ((e == 11) ? -1.0f : 1.0f) : 0.0f;

    int    lbase = ((t >> 4) << 2) + comp;            // dword idx; += 64 per k
    float* ob    = out + ((size_t)ray0 << 4) + t;     // += 256 per k

    if (ray0 + 256 <= n) {                            // full block
        #pragma unroll
        for (int k = 0; k < 16; ++k)
            ob[k << 8] = m * lds[lbase + (k << 6)];
    } else {                                          // tail block
        for (int k = 0; k < 16; ++k) {
            int rl = (t >> 4) + (k << 4);
            if (ray0 + rl < n)
                ob[k << 8] = m * lds[lbase + (k << 6)];
        }
    }
}

extern "C" void kernel_launch(void* const* d_in, const int* in_sizes, int n_in,
                              void* d_out, int out_size, void* d_ws, size_t ws_size,
                              hipStream_t stream) {
    const float* ci  = (const float*)d_in[0];
    const float* eta = (const float*)d_in[1];
    float* out = (float*)d_out;
    int n = in_sizes[0];
    int block = 256;
    int grid = (n + block - 1) / block;    // 256 rays per block
    mueller_kernel<<<grid, block, 0, stream>>>(ci, eta, out, n);
}